// Round 1
// baseline (232.044 us; speedup 1.0000x reference)
//
#include <hip/hip_runtime.h>
#include <math.h>

#define B_ 32
#define M_ 64
#define N_ 5000
#define L_ 100
#define H_ 8
#define D_ 16
#define E_ 128
#define IKS 133   // init_k LDS row stride (odd*... -> 5*dl mod 32 != 0 for dl<32: <=2-way conflicts)

struct P1 { unsigned int u[N_]; unsigned int hist[4096]; };
struct P2 {
  float initk[L_ * IKS];   // 53200 B
  float score[H_ * L_];    // 3200 B (reused as softmax weights w)
  float wk[H_ * E_];       // 4096 B
  float att[H_ * D_];      // 512 B
  float mh[E_];            // 512 B
  float s2[L_];            // 400 B
};
union SMem { P1 p1; P2 p2; float rowbuf[N_]; };

// ---- kernel 0: pos table [L,E] and qW[h,e] = (q_h . Wk_h)/sqrt(D) into ws ----
__global__ __launch_bounds__(256) void precomp_kernel(
    const float* __restrict__ Wq, const float* __restrict__ Wk,
    const float* __restrict__ cur, float* __restrict__ pos, float* __restrict__ qW)
{
  __shared__ float qs[H_ * D_];
  const int tid = threadIdx.x;
  if (tid < H_ * D_) {
    float acc = 0.f;
    for (int e = 0; e < E_; ++e) acc = fmaf(Wq[tid * E_ + e], cur[e], acc);
    qs[tid] = acc;
  }
  __syncthreads();
  for (int t = tid; t < H_ * E_; t += 256) {
    int h = t >> 7, e = t & 127;
    float acc = 0.f;
    for (int d = 0; d < D_; ++d) acc = fmaf(qs[h * D_ + d], Wk[(h * D_ + d) * E_ + e], acc);
    qW[t] = acc * 0.25f;  // fold 1/sqrt(D)
  }
  const float log_inc = 0.14619588050755848f;  // ln(10000)/63
  for (int t = tid; t < L_ * E_; t += 256) {
    int l = t >> 7, e = t & 127;
    int j = e & 63;
    float scaled = (float)l * expf(-(float)j * log_inc);
    pos[t] = (e < 64) ? sinf(scaled) : cosf(scaled);
  }
}

// ---- main kernel: one block per (b,m) row ----
__global__ __launch_bounds__(256) void local_att_kernel(
    const float* __restrict__ dist, const float* __restrict__ theta,
    const float* __restrict__ ninf, const float* __restrict__ Wi,
    const float* __restrict__ bi, const float* __restrict__ Wv,
    const float* __restrict__ Wc, const float* __restrict__ bcv,
    const float* __restrict__ pos, const float* __restrict__ qW,
    float* __restrict__ out)
{
  __shared__ SMem sm;
  __shared__ unsigned long long sel64[128];
  __shared__ int idxs[128];
  __shared__ float sdv[128], stv[128], smv[128];
  __shared__ unsigned int s_chosen, s_cumbefore, s_cnt;
  __shared__ unsigned int wsum[4];

  const int tid = threadIdx.x;
  const int r = blockIdx.x;
  const size_t base = (size_t)r * N_;

  // ---- Phase A: load d = dist - ninf, monotone-map f32 bits -> u32 ----
  const float4* d4 = (const float4*)(dist + base);
  const float4* n4 = (const float4*)(ninf + base);
  for (int i4 = tid; i4 < N_ / 4; i4 += 256) {
    float4 dv = d4[i4], nv = n4[i4];
    float vv[4] = {dv.x - nv.x, dv.y - nv.y, dv.z - nv.z, dv.w - nv.w};
    uint4 uu;
    unsigned int* up = (unsigned int*)&uu;
#pragma unroll
    for (int c = 0; c < 4; ++c) {
      unsigned int b = __float_as_uint(vv[c]);
      up[c] = (b & 0x80000000u) ? ~b : (b | 0x80000000u);
    }
    ((uint4*)sm.p1.u)[i4] = uu;
  }
  __syncthreads();

  // ---- Phase B: radix select on 45-bit key (u<<13)|i, 4 x 12-bit passes ----
  unsigned long long prefix = 0ull;
  unsigned int Krem = L_;
  for (int pass = 0; pass < 4; ++pass) {
    const int shift = 36 - 12 * pass;
    for (int j = tid; j < 4096; j += 256) sm.p1.hist[j] = 0u;
    __syncthreads();
    for (int i = tid; i < N_; i += 256) {
      unsigned long long key = ((unsigned long long)sm.p1.u[i] << 13) | (unsigned int)i;
      if ((key >> (shift + 12)) == prefix)
        atomicAdd(&sm.p1.hist[(unsigned int)(key >> shift) & 0xFFFu], 1u);
    }
    __syncthreads();
    // parallel prefix over 256 segments of 16 bins, find crossing
    unsigned int s = 0;
    for (int k2 = 0; k2 < 16; ++k2) s += sm.p1.hist[tid * 16 + k2];
    unsigned int v = s;
    const int lane = tid & 63, w = tid >> 6;
    for (int off = 1; off < 64; off <<= 1) {
      unsigned int x = __shfl_up(v, off, 64);
      if (lane >= off) v += x;
    }
    if (lane == 63) wsum[w] = v;
    __syncthreads();
    unsigned int add = 0;
    for (int ww = 0; ww < w; ++ww) add += wsum[ww];
    v += add;
    const unsigned int cumBefore = v - s;
    if (cumBefore < Krem && v >= Krem) {   // exactly one thread
      unsigned int c = cumBefore;
      int b = tid * 16;
      for (;; ++b) { unsigned int h = sm.p1.hist[b]; if (c + h >= Krem) break; c += h; }
      s_chosen = (unsigned int)b; s_cumbefore = c;
    }
    __syncthreads();
    prefix = (prefix << 12) | s_chosen;
    Krem -= s_cumbefore;
    __syncthreads();
  }
  const unsigned long long pivot = prefix;  // the 100th-smallest composite key

  // ---- Phase C: compact keys <= pivot (exactly 100, distinct), bitonic sort ----
  if (tid == 0) s_cnt = 0u;
  if (tid < 128) sel64[tid] = ~0ull;
  __syncthreads();
  for (int i = tid; i < N_; i += 256) {
    unsigned long long key = ((unsigned long long)sm.p1.u[i] << 13) | (unsigned int)i;
    if (key <= pivot) {
      unsigned int p = atomicAdd(&s_cnt, 1u);
      if (p < 128u) sel64[p] = key;
    }
  }
  __syncthreads();
  for (int k = 2; k <= 128; k <<= 1) {
    for (int j = k >> 1; j > 0; j >>= 1) {
      if (tid < 128) {
        int ixj = tid ^ j;
        if (ixj > tid) {
          unsigned long long a = sel64[tid], b2 = sel64[ixj];
          bool up = ((tid & k) == 0);
          if ((a > b2) == up) { sel64[tid] = b2; sel64[ixj] = a; }
        }
      }
      __syncthreads();
    }
  }

  // ---- Phase D: extract sorted (d, idx), gather theta/mask, normalize ----
  if (tid < L_) {
    unsigned long long key = sel64[tid];
    int idx = (int)(key & 0x1FFFull);
    unsigned int u = (unsigned int)(key >> 13);
    unsigned int bits = (u & 0x80000000u) ? (u ^ 0x80000000u) : ~u;
    idxs[tid] = idx;
    sdv[tid] = __uint_as_float(bits);
    stv[tid] = theta[base + idx];
    smv[tid] = ninf[base + idx];
  }
  __syncthreads();
  const float nrm = sdv[L_ - 1] + 1e-6f;   // max of ascending sorted dists
  __syncthreads();
  if (tid < L_) sdv[tid] = sdv[tid] / nrm;
  __syncthreads();

  // ---- Phase E: init_k[l,e] = sd*W0 + st*W1 + b + pos  (overwrites p1) ----
  for (int t = tid; t < L_ * E_; t += 256) {
    int l = t >> 7, e = t & 127;
    sm.p2.initk[l * IKS + e] =
        fmaf(sdv[l], Wi[2 * e], fmaf(stv[l], Wi[2 * e + 1], bi[e] + pos[t]));
  }
  __syncthreads();

  // ---- Phase F: score[h,l] = init_k[l,:].qW[h,:] + mask[l] (thread = l, 8 acc) ----
  if (tid < L_) {
    float acc[H_] = {0.f, 0.f, 0.f, 0.f, 0.f, 0.f, 0.f, 0.f};
    const float* ik = &sm.p2.initk[tid * IKS];
    for (int e = 0; e < E_; ++e) {
      float x = ik[e];
#pragma unroll
      for (int h = 0; h < H_; ++h) acc[h] = fmaf(x, qW[h * E_ + e], acc[h]);
    }
#pragma unroll
    for (int h = 0; h < H_; ++h) sm.p2.score[h * L_ + tid] = acc[h] + smv[tid];
  }
  __syncthreads();

  // ---- Phase G: softmax over l per head (32-lane group per head) ----
  {
    const int h = tid >> 5, l32 = tid & 31;
    float* sc = &sm.p2.score[h * L_];
    float mx = -INFINITY;
    for (int l = l32; l < L_; l += 32) mx = fmaxf(mx, sc[l]);
    for (int off = 16; off > 0; off >>= 1) mx = fmaxf(mx, __shfl_xor(mx, off, 32));
    float sum = 0.f;
    for (int l = l32; l < L_; l += 32) { float ex = expf(sc[l] - mx); sc[l] = ex; sum += ex; }
    for (int off = 16; off > 0; off >>= 1) sum += __shfl_xor(sum, off, 32);
    const float inv = 1.f / sum;
    for (int l = l32; l < L_; l += 32) sc[l] *= inv;
  }
  __syncthreads();

  // ---- Phase H: wk[h,e] = sum_l w[h,l]*init_k[l,e] (thread = e, 8 acc) ----
  if (tid < E_) {
    float acc[H_] = {0.f, 0.f, 0.f, 0.f, 0.f, 0.f, 0.f, 0.f};
    for (int l = 0; l < L_; ++l) {
      float x = sm.p2.initk[l * IKS + tid];
#pragma unroll
      for (int h = 0; h < H_; ++h) acc[h] = fmaf(x, sm.p2.score[h * L_ + l], acc[h]);
    }
#pragma unroll
    for (int h = 0; h < H_; ++h) sm.p2.wk[h * E_ + tid] = acc[h];
  }
  __syncthreads();

  // ---- Phase I: att[hd] = wk[h,:].Wv[hd,:]; mh[e] = bc[e] + att.Wc[e,:] ----
  if (tid < H_ * D_) {
    const int hd = tid, h = hd >> 4;
    float acc = 0.f;
    const float* wke = &sm.p2.wk[h * E_];
    const float* wvr = &Wv[hd * E_];
    for (int e = 0; e < E_; ++e) acc = fmaf(wke[e], wvr[e], acc);
    sm.p2.att[hd] = acc;
  }
  __syncthreads();
  if (tid < E_) {
    float acc = bcv[tid];
    const float* wcr = &Wc[tid * (H_ * D_)];
    for (int hd = 0; hd < H_ * D_; ++hd) acc = fmaf(sm.p2.att[hd], wcr[hd], acc);
    sm.p2.mh[tid] = acc;
  }
  __syncthreads();

  // ---- Phase J: score2[l] = (mh . init_k[l,:]) / sqrt(E) ----
  if (tid < L_) {
    float acc = 0.f;
    const float* ik = &sm.p2.initk[tid * IKS];
    for (int e = 0; e < E_; ++e) acc = fmaf(sm.p2.mh[e], ik[e], acc);
    sm.p2.s2[tid] = acc * 0.08838834764831845f;
  }
  __syncthreads();

  // ---- Phase K: build full row (zeros + scatter) in LDS, coalesced store ----
  for (int i = tid; i < N_; i += 256) sm.rowbuf[i] = 0.f;   // overlaps dead initk only
  __syncthreads();
  if (tid < L_) sm.rowbuf[idxs[tid]] = sm.p2.s2[tid];
  __syncthreads();
  float4* o4 = (float4*)(out + base);
  const float4* rb4 = (const float4*)sm.rowbuf;
  for (int i4 = tid; i4 < N_ / 4; i4 += 256) o4[i4] = rb4[i4];
}

extern "C" void kernel_launch(void* const* d_in, const int* in_sizes, int n_in,
                              void* d_out, int out_size, void* d_ws, size_t ws_size,
                              hipStream_t stream) {
  const float* dist = (const float*)d_in[0];
  const float* theta = (const float*)d_in[1];
  const float* ninf = (const float*)d_in[2];
  const float* Wi   = (const float*)d_in[3];
  const float* bi   = (const float*)d_in[4];
  const float* cur  = (const float*)d_in[5];
  const float* Wq   = (const float*)d_in[6];
  const float* Wk   = (const float*)d_in[7];
  const float* Wv   = (const float*)d_in[8];
  const float* Wc   = (const float*)d_in[9];
  const float* bcv  = (const float*)d_in[10];
  float* out = (float*)d_out;

  float* pos = (float*)d_ws;           // L*E floats
  float* qW  = pos + L_ * E_;          // H*E floats  (total 55.3 KB of ws)

  precomp_kernel<<<dim3(1), dim3(256), 0, stream>>>(Wq, Wk, cur, pos, qW);
  local_att_kernel<<<dim3(B_ * M_), dim3(256), 0, stream>>>(
      dist, theta, ninf, Wi, bi, Wv, Wc, bcv, pos, qW, out);
}

// Round 2
// 100.482 us; speedup vs baseline: 2.3093x; 2.3093x over previous
//
#include <hip/hip_runtime.h>
#include <math.h>

#define B_ 32
#define M_ 64
#define N_ 5000
#define L_ 100
#define H_ 8
#define D_ 16
#define E_ 128
#define NBIN 2048

// ---- workspace float offsets ----
#define OFF_QW    0        // [8*128]
#define OFF_POSQ  1024     // [8*100]  layout [h][l]
#define OFF_C0    1824     // [8]
#define OFF_C1    1832     // [8]
#define OFF_C2    1840     // [8]
#define OFF_PV0   1848     // [128]
#define OFF_PV1   1976     // [128]
#define OFF_PVB   2104     // [128]
#define OFF_WC0   2232     // [128]
#define OFF_WC1   2360     // [128]
#define OFF_WCB   2488     // [128]
#define OFF_SB    2616     // [3]  (W0.bc, W1.bc, b.bc)
#define OFF_PCB   2620     // [100]  pos[l,:].bc
#define OFF_PV    2720     // [100*128] PV[l][hd] = pos[l,:].Wv[hd,:]
#define OFF_PCT   15520    // [128*100] PCt[hd][l] = pos[l,:].Wc[:,hd]

__device__ __forceinline__ int vbin(float v) {
  if (!(v >= 0.f)) return 0;
  if (v >= 1.0f) return NBIN - 1;
  return (int)(v * (float)NBIN);
}

// ---- precomp1: q-folded tables (1 block) ----
__global__ __launch_bounds__(256) void precomp1(
    const float* __restrict__ Wq, const float* __restrict__ Wk,
    const float* __restrict__ cur, const float* __restrict__ Wi,
    const float* __restrict__ bi, const float* __restrict__ Wv,
    const float* __restrict__ Wc, const float* __restrict__ bc,
    float* __restrict__ ws)
{
  __shared__ float qs[H_ * D_];
  __shared__ float qwS[H_ * E_];
  const int tid = threadIdx.x;
  if (tid < H_ * D_) {
    float acc = 0.f;
    for (int e = 0; e < E_; ++e) acc = fmaf(Wq[tid * E_ + e], cur[e], acc);
    qs[tid] = acc;
  }
  __syncthreads();
  for (int t = tid; t < H_ * E_; t += 256) {
    int h = t >> 7, e = t & 127;
    float acc = 0.f;
    for (int d = 0; d < D_; ++d) acc = fmaf(qs[h * D_ + d], Wk[(h * D_ + d) * E_ + e], acc);
    acc *= 0.25f;                       // fold 1/sqrt(D)
    qwS[t] = acc; ws[OFF_QW + t] = acc;
  }
  __syncthreads();
  if (tid < H_) {
    float a0 = 0.f, a1 = 0.f, a2 = 0.f;
    for (int e = 0; e < E_; ++e) {
      float q = qwS[tid * E_ + e];
      a0 = fmaf(Wi[2 * e], q, a0); a1 = fmaf(Wi[2 * e + 1], q, a1); a2 = fmaf(bi[e], q, a2);
    }
    ws[OFF_C0 + tid] = a0; ws[OFF_C1 + tid] = a1; ws[OFF_C2 + tid] = a2;
  }
  if (tid >= 128 && tid < 256) {
    const int hd = tid - 128;
    float p0 = 0.f, p1 = 0.f, pb = 0.f, w0 = 0.f, w1 = 0.f, wb = 0.f;
    for (int e = 0; e < E_; ++e) {
      float wv = Wv[hd * E_ + e], wc = Wc[e * (H_ * D_) + hd];
      p0 = fmaf(Wi[2 * e], wv, p0); p1 = fmaf(Wi[2 * e + 1], wv, p1); pb = fmaf(bi[e], wv, pb);
      w0 = fmaf(Wi[2 * e], wc, w0); w1 = fmaf(Wi[2 * e + 1], wc, w1); wb = fmaf(bi[e], wc, wb);
    }
    ws[OFF_PV0 + hd] = p0; ws[OFF_PV1 + hd] = p1; ws[OFF_PVB + hd] = pb;
    ws[OFF_WC0 + hd] = w0; ws[OFF_WC1 + hd] = w1; ws[OFF_WCB + hd] = wb;
  }
  if (tid == 64) {
    float a = 0.f, b2 = 0.f, c = 0.f;
    for (int e = 0; e < E_; ++e) {
      a = fmaf(Wi[2 * e], bc[e], a); b2 = fmaf(Wi[2 * e + 1], bc[e], b2); c = fmaf(bi[e], bc[e], c);
    }
    ws[OFF_SB + 0] = a; ws[OFF_SB + 1] = b2; ws[OFF_SB + 2] = c;
  }
}

// ---- precomp2: positional-coupled tables (100 blocks, one per l) ----
__global__ __launch_bounds__(128) void precomp2(
    const float* __restrict__ Wv, const float* __restrict__ Wc,
    const float* __restrict__ bc, float* __restrict__ ws)
{
  const int l = blockIdx.x, tid = threadIdx.x;
  __shared__ float pr[E_];
  const float log_inc = 0.14619588050755848f;    // ln(10000)/63
  {
    int j = tid & 63;
    float scaled = (float)l * expf(-(float)j * log_inc);
    pr[tid] = (tid < 64) ? sinf(scaled) : cosf(scaled);
  }
  __syncthreads();
  float accv = 0.f, accc = 0.f;
  for (int e = 0; e < E_; ++e) {
    float p = pr[e];
    accv = fmaf(p, Wv[tid * E_ + e], accv);
    accc = fmaf(p, Wc[e * (H_ * D_) + tid], accc);
  }
  ws[OFF_PV + l * (H_ * D_) + tid] = accv;
  ws[OFF_PCT + tid * L_ + l] = accc;
  if (tid < H_) {
    float a = 0.f;
    for (int e = 0; e < E_; ++e) a = fmaf(pr[e], ws[OFF_QW + tid * E_ + e], a);
    ws[OFF_POSQ + tid * L_ + l] = a;
  }
  if (tid == 8) {
    float a = 0.f;
    for (int e = 0; e < E_; ++e) a = fmaf(pr[e], bc[e], a);
    ws[OFF_PCB + l] = a;
  }
}

// ---- main kernel: one block per (b,m) row ----
union R1 { unsigned int u[N_]; float rowbuf[N_]; };
union R2 {
  unsigned int hist[NBIN];
  struct { float score[H_ * L_]; float att[H_ * D_]; float a0[H_]; float a1[H_]; } a;
};

__global__ __launch_bounds__(256, 5) void local_att_kernel(
    const float* __restrict__ dist, const float* __restrict__ theta,
    const float* __restrict__ ninf, const float* __restrict__ ws,
    float* __restrict__ out)
{
  __shared__ R1 r1;
  __shared__ R2 r2;
  __shared__ unsigned long long sel64[128];
  __shared__ float sdv[128], stv[128], smv[128];
  __shared__ int idxs[128];
  __shared__ unsigned int wsum[4];
  __shared__ int s_bstar;
  __shared__ unsigned int s_cumB, s_binc, s_chosen, s_cumb2, s_cnt;
  __shared__ float s_norm, s_m0, s_m1, s_mb;

  const int tid = threadIdx.x;
  const size_t base = (size_t)blockIdx.x * N_;

  for (int j = tid; j < NBIN; j += 256) r2.hist[j] = 0u;
  __syncthreads();

  // ---- A: stream load, monotone u-map, fused value-bin histogram ----
  const float4* d4 = (const float4*)(dist + base);
  const float4* n4 = (const float4*)(ninf + base);
  for (int i4 = tid; i4 < N_ / 4; i4 += 256) {
    float4 dv = d4[i4], nv = n4[i4];
    float vv[4] = {dv.x - nv.x, dv.y - nv.y, dv.z - nv.z, dv.w - nv.w};
    unsigned int uu[4];
#pragma unroll
    for (int c = 0; c < 4; ++c) {
      unsigned int b = __float_as_uint(vv[c]);
      uu[c] = (b & 0x80000000u) ? ~b : (b | 0x80000000u);
      atomicAdd(&r2.hist[vbin(vv[c])], 1u);
    }
    uint4 q; q.x = uu[0]; q.y = uu[1]; q.z = uu[2]; q.w = uu[3];
    *(uint4*)&r1.u[i4 * 4] = q;
  }
  __syncthreads();

  // ---- B: prefix-scan 2048 bins (8/thread), find pivot bin ----
  unsigned int h8[8]; unsigned int s = 0u;
#pragma unroll
  for (int k = 0; k < 8; ++k) { h8[k] = r2.hist[tid * 8 + k]; s += h8[k]; }
  if (tid < 128) sel64[tid] = ~0ull;
  if (tid == 0) s_cnt = 0u;
  unsigned int v = s;
  const int lane = tid & 63, wid = tid >> 6;
  for (int off = 1; off < 64; off <<= 1) { unsigned int x = __shfl_up(v, off, 64); if (lane >= off) v += x; }
  if (lane == 63) wsum[wid] = v;
  __syncthreads();
  { unsigned int add = 0; for (int ww = 0; ww < wid; ++ww) add += wsum[ww]; v += add; }
  {
    unsigned int cumB = v - s;
    if (cumB < (unsigned)L_ && v >= (unsigned)L_) {
      unsigned int c = cumB;
#pragma unroll
      for (int k = 0; k < 8; ++k) {
        unsigned int h = h8[k];
        if (c + h >= (unsigned)L_) { s_bstar = tid * 8 + k; s_cumB = c; s_binc = h; break; }
        c += h;
      }
    }
  }
  __syncthreads();
  const int bstar = s_bstar;
  const bool fb = (s_cumB + s_binc > 128u);   // block-uniform
  unsigned long long kpiv = ~0ull;

  // ---- exact fallback (never taken for uniform data): 6x8-bit composite radix ----
  if (fb) {
    unsigned long long prefix = 0ull; unsigned int Krem = L_;
    for (int pass = 0; pass < 6; ++pass) {
      const int shift = 40 - 8 * pass;
      r2.hist[tid] = 0u;
      __syncthreads();
      for (int i = tid; i < N_; i += 256) {
        unsigned long long key = ((unsigned long long)r1.u[i] << 16) | (unsigned int)i;
        if ((key >> (shift + 8)) == prefix)
          atomicAdd(&r2.hist[(unsigned int)(key >> shift) & 0xFFu], 1u);
      }
      __syncthreads();
      unsigned int ss = r2.hist[tid];
      unsigned int vv2 = ss;
      for (int off = 1; off < 64; off <<= 1) { unsigned int x = __shfl_up(vv2, off, 64); if (lane >= off) vv2 += x; }
      if (lane == 63) wsum[wid] = vv2;
      __syncthreads();
      { unsigned int ad = 0; for (int ww = 0; ww < wid; ++ww) ad += wsum[ww]; vv2 += ad; }
      unsigned int cb = vv2 - ss;
      if (cb < Krem && vv2 >= Krem) { s_chosen = (unsigned int)tid; s_cumb2 = cb; }
      __syncthreads();
      prefix = (prefix << 8) | s_chosen;
      Krem -= s_cumb2;
      __syncthreads();
    }
    kpiv = prefix;
  }

  // ---- C: compact candidates ----
  for (int i = tid; i < N_; i += 256) {
    unsigned int u = r1.u[i];
    unsigned long long key = ((unsigned long long)u << 16) | (unsigned int)i;
    bool cand;
    if (fb) cand = (key <= kpiv);
    else {
      unsigned int bits = (u & 0x80000000u) ? (u ^ 0x80000000u) : ~u;
      cand = (vbin(__uint_as_float(bits)) <= bstar);
    }
    if (cand) {
      unsigned int p = atomicAdd(&s_cnt, 1u);
      if (p < 128u) sel64[p] = key;
    }
  }
  __syncthreads();

  // ---- D: barrier-free rank-by-count sort (keys distinct); zero rowbuf ----
  if (tid < 128) {
    unsigned long long my = sel64[tid];
    if (my != ~0ull) {
      int rank = 0;
      for (int j = 0; j < 128; ++j) rank += (sel64[j] < my) ? 1 : 0;
      if (rank < 128) {
        unsigned int u = (unsigned int)(my >> 16);
        unsigned int bits = (u & 0x80000000u) ? (u ^ 0x80000000u) : ~u;
        sdv[rank] = __uint_as_float(bits);
        idxs[rank] = (int)(my & 0xFFFFull);
      }
    }
  }
  for (int i = tid; i < N_; i += 256) r1.rowbuf[i] = 0.f;
  __syncthreads();

  // ---- E: gather theta/mask at sorted idx; normalize sd ----
  if (tid < L_) { int ix = idxs[tid]; stv[tid] = theta[base + ix]; smv[tid] = ninf[base + ix]; }
  if (tid == 0) s_norm = sdv[L_ - 1] + 1e-6f;
  __syncthreads();
  if (tid < L_) sdv[tid] = sdv[tid] / s_norm;
  __syncthreads();

  // ---- F: score[h,l] = sd*c0 + st*c1 + c2 + posq + mask ----
  for (int t = tid; t < H_ * L_; t += 256) {
    int h = t / L_, l = t - h * L_;
    r2.a.score[t] = fmaf(sdv[l], ws[OFF_C0 + h],
                    fmaf(stv[l], ws[OFF_C1 + h],
                         ws[OFF_C2 + h] + ws[OFF_POSQ + t] + smv[l]));
  }
  __syncthreads();

  // ---- G: softmax per head (8 x 32-lane groups) + a0,a1 ----
  {
    const int h = tid >> 5, l32 = tid & 31;
    float* sc = &r2.a.score[h * L_];
    float mx = -INFINITY;
    for (int l = l32; l < L_; l += 32) mx = fmaxf(mx, sc[l]);
    for (int off = 16; off > 0; off >>= 1) mx = fmaxf(mx, __shfl_xor(mx, off, 32));
    float sum = 0.f;
    for (int l = l32; l < L_; l += 32) { float ex = expf(sc[l] - mx); sc[l] = ex; sum += ex; }
    for (int off = 16; off > 0; off >>= 1) sum += __shfl_xor(sum, off, 32);
    const float inv = 1.f / sum;
    float a0p = 0.f, a1p = 0.f;
    for (int l = l32; l < L_; l += 32) {
      float wv2 = sc[l] * inv; sc[l] = wv2;
      a0p = fmaf(wv2, sdv[l], a0p); a1p = fmaf(wv2, stv[l], a1p);
    }
    for (int off = 16; off > 0; off >>= 1) { a0p += __shfl_xor(a0p, off, 32); a1p += __shfl_xor(a1p, off, 32); }
    if (l32 == 0) { r2.a.a0[h] = a0p; r2.a.a1[h] = a1p; }
  }
  __syncthreads();

  // ---- H: att[hd] = a0*pv0 + a1*pv1 + pvb + sum_l w[h,l]*PV[l,hd] ----
  if (tid < H_ * D_) {
    const int hd = tid, h = hd >> 4;
    float acc = fmaf(r2.a.a0[h], ws[OFF_PV0 + hd], fmaf(r2.a.a1[h], ws[OFF_PV1 + hd], ws[OFF_PVB + hd]));
    const float* pv = ws + OFF_PV + hd;
    const float* wrow = &r2.a.score[h * L_];
#pragma unroll 4
    for (int l = 0; l < L_; ++l) acc = fmaf(wrow[l], pv[l * (H_ * D_)], acc);
    r2.a.att[hd] = acc;
  }
  __syncthreads();

  // ---- I: m0 = mh.W0, m1 = mh.W1, mb = mh.b via att-dots (wave 0) ----
  if (tid < 64) {
    float x0 = r2.a.att[tid], x1 = r2.a.att[tid + 64];
    float m0 = fmaf(x0, ws[OFF_WC0 + tid], x1 * ws[OFF_WC0 + tid + 64]);
    float m1 = fmaf(x0, ws[OFF_WC1 + tid], x1 * ws[OFF_WC1 + tid + 64]);
    float mb = fmaf(x0, ws[OFF_WCB + tid], x1 * ws[OFF_WCB + tid + 64]);
    for (int off = 32; off > 0; off >>= 1) {
      m0 += __shfl_xor(m0, off, 64);
      m1 += __shfl_xor(m1, off, 64);
      mb += __shfl_xor(mb, off, 64);
    }
    if (tid == 0) {
      s_m0 = m0 + ws[OFF_SB + 0]; s_m1 = m1 + ws[OFF_SB + 1]; s_mb = mb + ws[OFF_SB + 2];
    }
  }
  __syncthreads();

  // ---- J: s2[l] = (sd*m0 + st*m1 + mb + pcb + att.PCt[:,l]) / sqrt(E); scatter ----
  if (tid < L_) {
    float acc = ws[OFF_PCB + tid];
    const float* pct = ws + OFF_PCT + tid;
#pragma unroll 4
    for (int hd = 0; hd < H_ * D_; ++hd) acc = fmaf(r2.a.att[hd], pct[hd * L_], acc);
    float s2v = fmaf(sdv[tid], s_m0, fmaf(stv[tid], s_m1, s_mb + acc)) * 0.08838834764831845f;
    r1.rowbuf[idxs[tid]] = s2v;
  }
  __syncthreads();

  // ---- K: coalesced row write ----
  const float4* rb4 = (const float4*)r1.rowbuf;
  float4* o4 = (float4*)(out + base);
  for (int i4 = tid; i4 < N_ / 4; i4 += 256) o4[i4] = rb4[i4];
}

extern "C" void kernel_launch(void* const* d_in, const int* in_sizes, int n_in,
                              void* d_out, int out_size, void* d_ws, size_t ws_size,
                              hipStream_t stream) {
  const float* dist = (const float*)d_in[0];
  const float* theta = (const float*)d_in[1];
  const float* ninf = (const float*)d_in[2];
  const float* Wi   = (const float*)d_in[3];
  const float* bi   = (const float*)d_in[4];
  const float* cur  = (const float*)d_in[5];
  const float* Wq   = (const float*)d_in[6];
  const float* Wk   = (const float*)d_in[7];
  const float* Wv   = (const float*)d_in[8];
  const float* Wc   = (const float*)d_in[9];
  const float* bcv  = (const float*)d_in[10];
  float* out = (float*)d_out;
  float* ws  = (float*)d_ws;

  precomp1<<<dim3(1), dim3(256), 0, stream>>>(Wq, Wk, cur, Wi, bi, Wv, Wc, bcv, ws);
  precomp2<<<dim3(L_), dim3(128), 0, stream>>>(Wv, Wc, bcv, ws);
  local_att_kernel<<<dim3(B_ * M_), dim3(256), 0, stream>>>(dist, theta, ninf, ws, out);
}

// Round 3
// 83.557 us; speedup vs baseline: 2.7771x; 1.2026x over previous
//
#include <hip/hip_runtime.h>
#include <math.h>

#define B_ 32
#define M_ 64
#define N_ 5000
#define L_ 100
#define H_ 8
#define D_ 16
#define E_ 128
#define NBIN 2048
#define NT 512
#define NI4 1250   // N_/4

// ---- workspace float offsets ----
#define OFF_POSQ  0        // [8*100] layout [h][l]
#define OFF_C0    800      // [8]
#define OFF_C1    808      // [8]
#define OFF_C2    816      // [8]
#define OFF_PV0   824      // [128]
#define OFF_PV1   952      // [128]
#define OFF_PVB   1080     // [128]
#define OFF_WC0   1208     // [128]
#define OFF_WC1   1336     // [128]
#define OFF_WCB   1464     // [128]
#define OFF_SB    1592     // [3]
#define OFF_PCB   1596     // [100]
#define OFF_PV    1696     // [100*128]  PV[l][hd]
#define OFF_PCT   14496    // [128*100]  PCt[hd][l]

__device__ __forceinline__ int vbin(float v) {
  if (!(v >= 0.f)) return 0;
  if (v >= 1.0f) return NBIN - 1;
  return (int)(v * (float)NBIN);
}
__device__ __forceinline__ unsigned int umap(float v) {
  unsigned int b = __float_as_uint(v);
  return (b & 0x80000000u) ? ~b : (b | 0x80000000u);
}

// ---- fused precomp: block 0 = q-folded vectors; blocks 1..100 = per-l tables ----
__global__ __launch_bounds__(128) void precomp(
    const float* __restrict__ Wq, const float* __restrict__ Wk,
    const float* __restrict__ cur, const float* __restrict__ Wi,
    const float* __restrict__ bi, const float* __restrict__ Wv,
    const float* __restrict__ Wc, const float* __restrict__ bc,
    float* __restrict__ ws)
{
  const int tid = threadIdx.x;
  const int blk = blockIdx.x;
  __shared__ float pr[E_];
  __shared__ float red[8];
  const int lane = tid & 63, wv = tid >> 6;

  if (blk == 0) {
    // qs[hd] = Wq[hd,:].cur
    float qsv = 0.f;
    for (int e = 0; e < E_; ++e) qsv = fmaf(Wq[tid * E_ + e], cur[e], qsv);
    // row-dots of Wk/Wv/Wc with Wi0/Wi1/bi
    float wk0=0,wk1=0,wkb=0,pv0=0,pv1=0,pvb=0,wc0=0,wc1=0,wcb=0;
    for (int e = 0; e < E_; ++e) {
      float wi0 = Wi[2*e], wi1 = Wi[2*e+1], bie = bi[e];
      float wk = Wk[tid*E_+e], wvv = Wv[tid*E_+e], wcc = Wc[e*(H_*D_)+tid];
      wk0=fmaf(wk,wi0,wk0);  wk1=fmaf(wk,wi1,wk1);  wkb=fmaf(wk,bie,wkb);
      pv0=fmaf(wvv,wi0,pv0); pv1=fmaf(wvv,wi1,pv1); pvb=fmaf(wvv,bie,pvb);
      wc0=fmaf(wcc,wi0,wc0); wc1=fmaf(wcc,wi1,wc1); wcb=fmaf(wcc,bie,wcb);
    }
    ws[OFF_PV0+tid]=pv0; ws[OFF_PV1+tid]=pv1; ws[OFF_PVB+tid]=pvb;
    ws[OFF_WC0+tid]=wc0; ws[OFF_WC1+tid]=wc1; ws[OFF_WCB+tid]=wcb;
    // c*[h] = sum_d qs[hd]*wk*[hd] * 0.25  (16-lane reduce)
    float c0 = qsv*wk0, c1 = qsv*wk1, c2 = qsv*wkb;
    for (int off = 1; off < 16; off <<= 1) {
      c0 += __shfl_xor(c0, off, 16); c1 += __shfl_xor(c1, off, 16); c2 += __shfl_xor(c2, off, 16);
    }
    if ((tid & 15) == 0) {
      int h = tid >> 4;
      ws[OFF_C0+h] = c0*0.25f; ws[OFF_C1+h] = c1*0.25f; ws[OFF_C2+h] = c2*0.25f;
    }
    // SB: bc-dots with Wi0/Wi1/bi
    float p0 = Wi[2*tid]*bc[tid], p1 = Wi[2*tid+1]*bc[tid], p2 = bi[tid]*bc[tid];
    for (int off = 32; off > 0; off >>= 1) {
      p0 += __shfl_xor(p0, off, 64); p1 += __shfl_xor(p1, off, 64); p2 += __shfl_xor(p2, off, 64);
    }
    if (lane == 0) { red[wv*3+0]=p0; red[wv*3+1]=p1; red[wv*3+2]=p2; }
    __syncthreads();
    if (tid == 0) {
      ws[OFF_SB+0]=red[0]+red[3]; ws[OFF_SB+1]=red[1]+red[4]; ws[OFF_SB+2]=red[2]+red[5];
    }
  } else {
    const int l = blk - 1;
    const float log_inc = 0.14619588050755848f;   // ln(10000)/63
    {
      int j = tid & 63;
      float scaled = (float)l * expf(-(float)j * log_inc);
      pr[tid] = (tid < 64) ? sinf(scaled) : cosf(scaled);
    }
    __syncthreads();
    float qsv=0.f, pwk=0.f, accv=0.f, accc=0.f;
    for (int e = 0; e < E_; ++e) qsv = fmaf(Wq[tid*E_+e], cur[e], qsv);
    for (int e = 0; e < E_; ++e) {
      float p = pr[e];
      pwk  = fmaf(Wk[tid*E_+e], p, pwk);
      accv = fmaf(Wv[tid*E_+e], p, accv);
      accc = fmaf(Wc[e*(H_*D_)+tid], p, accc);
    }
    ws[OFF_PV  + l*(H_*D_) + tid] = accv;
    ws[OFF_PCT + tid*L_ + l] = accc;
    float pq = qsv * pwk;
    for (int off = 1; off < 16; off <<= 1) pq += __shfl_xor(pq, off, 16);
    if ((tid & 15) == 0) ws[OFF_POSQ + (tid>>4)*L_ + l] = pq * 0.25f;
    // pcb[l] = pr.bc
    float pb = pr[tid] * bc[tid];
    for (int off = 32; off > 0; off >>= 1) pb += __shfl_xor(pb, off, 64);
    if (lane == 0) red[wv] = pb;
    __syncthreads();
    if (tid == 0) ws[OFF_PCB + l] = red[0] + red[1];
  }
}

// ---- main kernel: one block per (b,m) row, 512 threads ----
union alignas(16) SU {
  struct { unsigned short bins[N_]; unsigned int hist[NBIN]; } s;  // 18192 B
  float rowbuf[N_];                                                 // 20000 B
  struct { float score[H_ * L_]; } a;                               // 3200 B
};

__global__ __launch_bounds__(NT, 8) void local_att_kernel(
    const float* __restrict__ dist, const float* __restrict__ theta,
    const float* __restrict__ ninf, const float* __restrict__ ws,
    float* __restrict__ out)
{
  __shared__ SU su;
  __shared__ unsigned long long sel64[128];
  __shared__ float sdv[128];
  __shared__ int idxs[128];
  __shared__ float stv[L_], smv[L_];
  __shared__ float att[H_ * D_], a0s[H_], a1s[H_];
  __shared__ unsigned int wsum[8];
  __shared__ int s_bstar;
  __shared__ unsigned int s_cumB, s_binc, s_chosen, s_cumb2, s_cnt;
  __shared__ float s_m0, s_m1, s_mb;

  const int tid = threadIdx.x;
  const int lane = tid & 63, wv = tid >> 6;
  const size_t base = (size_t)blockIdx.x * N_;
  const float4* d4 = (const float4*)(dist + base);
  const float4* n4 = (const float4*)(ninf + base);

  // ---- P0: init ----
  for (int j = tid; j < NBIN; j += NT) su.s.hist[j] = 0u;
  if (tid < 128) sel64[tid] = ~0ull;
  if (tid == 0) s_cnt = 0u;
  __syncthreads();

  // ---- P1: stream, bin, store u16 bins, histogram ----
#pragma unroll
  for (int k = 0; k < 3; ++k) {
    int i4 = tid + k * NT;
    if (i4 < NI4) {
      float4 dv = d4[i4], nv = n4[i4];
      float vv4[4] = {dv.x - nv.x, dv.y - nv.y, dv.z - nv.z, dv.w - nv.w};
      unsigned int bn[4];
#pragma unroll
      for (int c = 0; c < 4; ++c) {
        bn[c] = (unsigned int)vbin(vv4[c]);
        atomicAdd(&su.s.hist[bn[c]], 1u);
      }
      uint2 pk;
      pk.x = bn[0] | (bn[1] << 16);
      pk.y = bn[2] | (bn[3] << 16);
      *(uint2*)&su.s.bins[i4 * 4] = pk;
    }
  }
  __syncthreads();

  // ---- P2: scan 2048 bins (4/thread), pick pivot bin ----
  unsigned int h4[4]; unsigned int s = 0u;
#pragma unroll
  for (int k2 = 0; k2 < 4; ++k2) { h4[k2] = su.s.hist[tid * 4 + k2]; s += h4[k2]; }
  unsigned int v = s;
  for (int off = 1; off < 64; off <<= 1) { unsigned int x = __shfl_up(v, off, 64); if (lane >= off) v += x; }
  if (lane == 63) wsum[wv] = v;
  __syncthreads();
  { unsigned int add = 0; for (int ww = 0; ww < wv; ++ww) add += wsum[ww]; v += add; }
  {
    unsigned int cumB = v - s;
    if (cumB < (unsigned)L_ && v >= (unsigned)L_) {
      unsigned int c = cumB;
#pragma unroll
      for (int k2 = 0; k2 < 4; ++k2) {
        unsigned int hh = h4[k2];
        if (c + hh >= (unsigned)L_) { s_bstar = tid * 4 + k2; s_cumB = c; s_binc = hh; break; }
        c += hh;
      }
    }
  }
  __syncthreads();
  const int bstar = s_bstar;
  const bool fb = (s_cumB + s_binc > 128u);
  unsigned long long kpiv = ~0ull;

  // ---- exact fallback (rare): 6x8-bit radix, keys recomputed from global ----
  if (fb) {
    unsigned long long prefix = 0ull; unsigned int Krem = L_;
    for (int pass = 0; pass < 6; ++pass) {
      const int shift = 40 - 8 * pass;
      for (int j2 = tid; j2 < 256; j2 += NT) su.s.hist[j2] = 0u;
      __syncthreads();
#pragma unroll
      for (int k = 0; k < 3; ++k) {
        int i4 = tid + k * NT;
        if (i4 < NI4) {
          float4 dv = d4[i4], nv = n4[i4];
          float vv4[4] = {dv.x - nv.x, dv.y - nv.y, dv.z - nv.z, dv.w - nv.w};
#pragma unroll
          for (int c = 0; c < 4; ++c) {
            unsigned long long key = ((unsigned long long)umap(vv4[c]) << 16) | (unsigned)(i4 * 4 + c);
            if ((key >> (shift + 8)) == prefix)
              atomicAdd(&su.s.hist[(unsigned)(key >> shift) & 0xFFu], 1u);
          }
        }
      }
      __syncthreads();
      unsigned int ss = (tid < 256) ? su.s.hist[tid] : 0u;
      unsigned int vv = ss;
      for (int off = 1; off < 64; off <<= 1) { unsigned int x = __shfl_up(vv, off, 64); if (lane >= off) vv += x; }
      if (lane == 63) wsum[wv] = vv;
      __syncthreads();
      { unsigned int ad = 0; for (int ww = 0; ww < wv; ++ww) ad += wsum[ww]; vv += ad; }
      unsigned int cb = vv - ss;
      if (tid < 256 && cb < Krem && vv >= Krem) { s_chosen = (unsigned)tid; s_cumb2 = cb; }
      __syncthreads();
      prefix = (prefix << 8) | s_chosen;
      Krem -= s_cumb2;
      __syncthreads();
    }
    kpiv = prefix;
  }

  // ---- P4: compact candidates (bin test from LDS; exact key from global reload) ----
#pragma unroll
  for (int k = 0; k < 3; ++k) {
    int i4 = tid + k * NT;
    if (i4 < NI4) {
      if (!fb) {
        uint2 pk = *(const uint2*)&su.s.bins[i4 * 4];
        unsigned int b4[4] = {pk.x & 0xFFFFu, pk.x >> 16, pk.y & 0xFFFFu, pk.y >> 16};
#pragma unroll
        for (int c = 0; c < 4; ++c) {
          if ((int)b4[c] <= bstar) {
            int i = i4 * 4 + c;
            float vvv = dist[base + i] - ninf[base + i];
            unsigned long long key = ((unsigned long long)umap(vvv) << 16) | (unsigned)i;
            unsigned int p = atomicAdd(&s_cnt, 1u);
            if (p < 128u) sel64[p] = key;
          }
        }
      } else {
        float4 dv = d4[i4], nv = n4[i4];
        float vv4[4] = {dv.x - nv.x, dv.y - nv.y, dv.z - nv.z, dv.w - nv.w};
#pragma unroll
        for (int c = 0; c < 4; ++c) {
          unsigned long long key = ((unsigned long long)umap(vv4[c]) << 16) | (unsigned)(i4 * 4 + c);
          if (key <= kpiv) {
            unsigned int p = atomicAdd(&s_cnt, 1u);
            if (p < 128u) sel64[p] = key;
          }
        }
      }
    }
  }
  __syncthreads();

  // ---- P5: rank-by-count sort (keys distinct, <=128 candidates) ----
  if (tid < 128) {
    unsigned long long my = sel64[tid];
    if (my != ~0ull) {
      int rank = 0;
      for (int j = 0; j < 128; ++j) rank += (sel64[j] < my) ? 1 : 0;
      unsigned int u = (unsigned int)(my >> 16);
      unsigned int bits = (u & 0x80000000u) ? (u ^ 0x80000000u) : ~u;
      sdv[rank] = __uint_as_float(bits);
      idxs[rank] = (int)(my & 0xFFFFull);
    }
  }
  __syncthreads();

  const float invn = 1.0f / (sdv[L_ - 1] + 1e-6f);

  // ---- P6: gather theta/mask at sorted idx ----
  if (tid < L_) { int ix = idxs[tid]; stv[tid] = theta[base + ix]; smv[tid] = ninf[base + ix]; }
  __syncthreads();

  // ---- P7: score[h,l] = sdn*c0 + st*c1 + c2 + posq + mask ----
  for (int t = tid; t < H_ * L_; t += NT) {
    int h = t / L_, l = t - h * L_;
    su.a.score[t] = fmaf(sdv[l] * invn, ws[OFF_C0 + h],
                    fmaf(stv[l], ws[OFF_C1 + h],
                         ws[OFF_C2 + h] + ws[OFF_POSQ + t] + smv[l]));
  }
  __syncthreads();

  // ---- P8: softmax per head (8 heads x 64 lanes) + a0,a1 ----
  {
    const int h = wv, l64 = lane;
    float* sc = &su.a.score[h * L_];
    float mx = -INFINITY;
    for (int l = l64; l < L_; l += 64) mx = fmaxf(mx, sc[l]);
    for (int off = 32; off > 0; off >>= 1) mx = fmaxf(mx, __shfl_xor(mx, off, 64));
    float sum = 0.f;
    for (int l = l64; l < L_; l += 64) { float ex = expf(sc[l] - mx); sc[l] = ex; sum += ex; }
    for (int off = 32; off > 0; off >>= 1) sum += __shfl_xor(sum, off, 64);
    const float inv = 1.f / sum;
    float a0p = 0.f, a1p = 0.f;
    for (int l = l64; l < L_; l += 64) {
      float w2 = sc[l] * inv; sc[l] = w2;
      a0p = fmaf(w2, sdv[l] * invn, a0p); a1p = fmaf(w2, stv[l], a1p);
    }
    for (int off = 32; off > 0; off >>= 1) { a0p += __shfl_xor(a0p, off, 64); a1p += __shfl_xor(a1p, off, 64); }
    if (l64 == 0) { a0s[h] = a0p; a1s[h] = a1p; }
  }
  __syncthreads();

  // ---- P9: att[hd] = a0*pv0 + a1*pv1 + pvb + sum_l w[h,l]*PV[l,hd] ----
  if (tid < H_ * D_) {
    const int hd = tid, h = hd >> 4;
    float acc = fmaf(a0s[h], ws[OFF_PV0 + hd], fmaf(a1s[h], ws[OFF_PV1 + hd], ws[OFF_PVB + hd]));
    const float* pv = ws + OFF_PV + hd;
    const float* wrow = &su.a.score[h * L_];
#pragma unroll 4
    for (int l = 0; l < L_; ++l) acc = fmaf(wrow[l], pv[l * (H_ * D_)], acc);
    att[hd] = acc;
  }
  __syncthreads();

  // ---- P10: m0/m1/mb (tid<64)  ||  zero rowbuf (tid>=64) ----
  if (tid < 64) {
    float x0 = att[tid], x1 = att[tid + 64];
    float m0 = fmaf(x0, ws[OFF_WC0 + tid], x1 * ws[OFF_WC0 + tid + 64]);
    float m1 = fmaf(x0, ws[OFF_WC1 + tid], x1 * ws[OFF_WC1 + tid + 64]);
    float mb = fmaf(x0, ws[OFF_WCB + tid], x1 * ws[OFF_WCB + tid + 64]);
    for (int off = 32; off > 0; off >>= 1) {
      m0 += __shfl_xor(m0, off, 64); m1 += __shfl_xor(m1, off, 64); mb += __shfl_xor(mb, off, 64);
    }
    if (tid == 0) {
      s_m0 = m0 + ws[OFF_SB + 0]; s_m1 = m1 + ws[OFF_SB + 1]; s_mb = mb + ws[OFF_SB + 2];
    }
  } else {
    float4 z = {0.f, 0.f, 0.f, 0.f};
    for (int i4 = tid - 64; i4 < NI4; i4 += NT - 64) ((float4*)su.rowbuf)[i4] = z;
  }
  __syncthreads();

  // ---- P11: s2[l] + scatter into rowbuf ----
  if (tid < L_) {
    float acc = ws[OFF_PCB + tid];
    const float* pct = ws + OFF_PCT + tid;
#pragma unroll 4
    for (int hd = 0; hd < H_ * D_; ++hd) acc = fmaf(att[hd], pct[hd * L_], acc);
    float s2v = fmaf(sdv[tid] * invn, s_m0, fmaf(stv[tid], s_m1, s_mb + acc)) * 0.08838834764831845f;
    su.rowbuf[idxs[tid]] = s2v;
  }
  __syncthreads();

  // ---- P12: coalesced row write ----
  const float4* rb4 = (const float4*)su.rowbuf;
  float4* o4 = (float4*)(out + base);
  for (int i4 = tid; i4 < NI4; i4 += NT) o4[i4] = rb4[i4];
}

extern "C" void kernel_launch(void* const* d_in, const int* in_sizes, int n_in,
                              void* d_out, int out_size, void* d_ws, size_t ws_size,
                              hipStream_t stream) {
  const float* dist = (const float*)d_in[0];
  const float* theta = (const float*)d_in[1];
  const float* ninf = (const float*)d_in[2];
  const float* Wi   = (const float*)d_in[3];
  const float* bi   = (const float*)d_in[4];
  const float* cur  = (const float*)d_in[5];
  const float* Wq   = (const float*)d_in[6];
  const float* Wk   = (const float*)d_in[7];
  const float* Wv   = (const float*)d_in[8];
  const float* Wc   = (const float*)d_in[9];
  const float* bcv  = (const float*)d_in[10];
  float* out = (float*)d_out;
  float* ws  = (float*)d_ws;

  precomp<<<dim3(L_ + 1), dim3(128), 0, stream>>>(Wq, Wk, cur, Wi, bi, Wv, Wc, bcv, ws);
  local_att_kernel<<<dim3(B_ * M_), dim3(NT), 0, stream>>>(dist, theta, ninf, ws, out);
}

// Round 4
// 79.764 us; speedup vs baseline: 2.9091x; 1.0476x over previous
//
#include <hip/hip_runtime.h>
#include <math.h>

#define B_ 32
#define M_ 64
#define N_ 5000
#define L_ 100
#define H_ 8
#define D_ 16
#define E_ 128
#define NBIN 1024
#define NI4 1250   // N_/4
#define RPB 8      // rows (waves) per block

// ---- workspace float offsets ----
#define OFF_POSQ  0        // [8*100] layout [h][l]
#define OFF_C0    800      // [8]
#define OFF_C1    808      // [8]
#define OFF_C2    816      // [8]
#define OFF_PV0   824      // [128]
#define OFF_PV1   952      // [128]
#define OFF_PVB   1080     // [128]
#define OFF_WC0   1208     // [128]
#define OFF_WC1   1336     // [128]
#define OFF_WCB   1464     // [128]
#define OFF_SB    1592     // [3]
#define OFF_PCB   1596     // [100]
#define OFF_PV    1696     // [100*128]  PV[l][hd]
#define OFF_PCT   14496    // [128*100]  PCt[hd][l]

// wave-internal phase sync: order LDS ops; sched_barrier stops hoisting (rule #18)
#define WSYNC() do { asm volatile("s_waitcnt lgkmcnt(0)" ::: "memory"); __builtin_amdgcn_sched_barrier(0); } while (0)
#define VSYNC() do { asm volatile("s_waitcnt vmcnt(0)" ::: "memory"); __builtin_amdgcn_sched_barrier(0); } while (0)

__device__ __forceinline__ int vbin(float v) {
  if (!(v >= 0.f)) return 0;
  if (v >= 1.0f) return NBIN - 1;
  return (int)(v * (float)NBIN);
}
__device__ __forceinline__ unsigned int umap(float v) {
  unsigned int b = __float_as_uint(v);
  return (b & 0x80000000u) ? ~b : (b | 0x80000000u);
}
// bank-conflict-free hist layouts: lane sums bins {lane*16+k} at phys {k*64+lane}
#define HMAP(b)  ((((b) & 15) << 6) + ((b) >> 4))
#define HMAP4(b) ((((b) & 3) << 6) + ((b) >> 2))

// ---- fused precomp: block 0 = q-folded vectors; blocks 1..100 = per-l tables ----
__global__ __launch_bounds__(128) void precomp(
    const float* __restrict__ Wq, const float* __restrict__ Wk,
    const float* __restrict__ cur, const float* __restrict__ Wi,
    const float* __restrict__ bi, const float* __restrict__ Wv,
    const float* __restrict__ Wc, const float* __restrict__ bc,
    float* __restrict__ ws)
{
  const int tid = threadIdx.x;
  const int blk = blockIdx.x;
  __shared__ float pr[E_];
  __shared__ float red[8];
  const int lane = tid & 63, wvv = tid >> 6;

  if (blk == 0) {
    float qsv = 0.f;
    for (int e = 0; e < E_; ++e) qsv = fmaf(Wq[tid * E_ + e], cur[e], qsv);
    float wk0=0,wk1=0,wkb=0,pv0=0,pv1=0,pvb=0,wc0=0,wc1=0,wcb=0;
    for (int e = 0; e < E_; ++e) {
      float wi0 = Wi[2*e], wi1 = Wi[2*e+1], bie = bi[e];
      float wk = Wk[tid*E_+e], wvx = Wv[tid*E_+e], wcc = Wc[e*(H_*D_)+tid];
      wk0=fmaf(wk,wi0,wk0);  wk1=fmaf(wk,wi1,wk1);  wkb=fmaf(wk,bie,wkb);
      pv0=fmaf(wvx,wi0,pv0); pv1=fmaf(wvx,wi1,pv1); pvb=fmaf(wvx,bie,pvb);
      wc0=fmaf(wcc,wi0,wc0); wc1=fmaf(wcc,wi1,wc1); wcb=fmaf(wcc,bie,wcb);
    }
    ws[OFF_PV0+tid]=pv0; ws[OFF_PV1+tid]=pv1; ws[OFF_PVB+tid]=pvb;
    ws[OFF_WC0+tid]=wc0; ws[OFF_WC1+tid]=wc1; ws[OFF_WCB+tid]=wcb;
    float c0 = qsv*wk0, c1 = qsv*wk1, c2 = qsv*wkb;
    for (int off = 1; off < 16; off <<= 1) {
      c0 += __shfl_xor(c0, off, 16); c1 += __shfl_xor(c1, off, 16); c2 += __shfl_xor(c2, off, 16);
    }
    if ((tid & 15) == 0) {
      int h = tid >> 4;
      ws[OFF_C0+h] = c0*0.25f; ws[OFF_C1+h] = c1*0.25f; ws[OFF_C2+h] = c2*0.25f;
    }
    float p0 = Wi[2*tid]*bc[tid], p1 = Wi[2*tid+1]*bc[tid], p2 = bi[tid]*bc[tid];
    for (int off = 32; off > 0; off >>= 1) {
      p0 += __shfl_xor(p0, off, 64); p1 += __shfl_xor(p1, off, 64); p2 += __shfl_xor(p2, off, 64);
    }
    if (lane == 0) { red[wvv*3+0]=p0; red[wvv*3+1]=p1; red[wvv*3+2]=p2; }
    __syncthreads();
    if (tid == 0) {
      ws[OFF_SB+0]=red[0]+red[3]; ws[OFF_SB+1]=red[1]+red[4]; ws[OFF_SB+2]=red[2]+red[5];
    }
  } else {
    const int l = blk - 1;
    const float log_inc = 0.14619588050755848f;   // ln(10000)/63
    {
      int j = tid & 63;
      float scaled = (float)l * expf(-(float)j * log_inc);
      pr[tid] = (tid < 64) ? sinf(scaled) : cosf(scaled);
    }
    __syncthreads();
    float qsv=0.f, pwk=0.f, accv=0.f, accc=0.f;
    for (int e = 0; e < E_; ++e) qsv = fmaf(Wq[tid*E_+e], cur[e], qsv);
    for (int e = 0; e < E_; ++e) {
      float p = pr[e];
      pwk  = fmaf(Wk[tid*E_+e], p, pwk);
      accv = fmaf(Wv[tid*E_+e], p, accv);
      accc = fmaf(Wc[e*(H_*D_)+tid], p, accc);
    }
    ws[OFF_PV  + l*(H_*D_) + tid] = accv;
    ws[OFF_PCT + tid*L_ + l] = accc;
    float pq = qsv * pwk;
    for (int off = 1; off < 16; off <<= 1) pq += __shfl_xor(pq, off, 16);
    if ((tid & 15) == 0) ws[OFF_POSQ + (tid>>4)*L_ + l] = pq * 0.25f;
    float pb = pr[tid] * bc[tid];
    for (int off = 32; off > 0; off >>= 1) pb += __shfl_xor(pb, off, 64);
    if (lane == 0) red[wvv] = pb;
    __syncthreads();
    if (tid == 0) ws[OFF_PCB + l] = red[0] + red[1];
  }
}

// ---- main kernel: ONE WAVE PER ROW, zero block barriers ----
__global__ __launch_bounds__(512) void local_att_kernel(
    const float* __restrict__ dist, const float* __restrict__ theta,
    const float* __restrict__ ninf, const float* __restrict__ ws,
    float* __restrict__ out)
{
  // per-row 4KB arena (word map): hist 0..1023 (dead after pivot; fb-hist 0..255)
  //   sel64 @ words 256..511 | sdv @520 idxs @648 stv @776 smv @876 | att @0..127
  __shared__ alignas(16) unsigned int arena[RPB][1024];
  __shared__ unsigned int cnt8[RPB];

  const int tid  = threadIdx.x;
  const int lane = tid & 63;
  const int wv   = tid >> 6;
  const size_t base = (size_t)(blockIdx.x * RPB + wv) * N_;
  unsigned int* hist = arena[wv];
  unsigned long long* sel = (unsigned long long*)&arena[wv][256];
  float* sdv = (float*)&arena[wv][520];
  unsigned int* idxs = &arena[wv][648];
  float* stv = (float*)&arena[wv][776];
  float* smv = (float*)&arena[wv][876];
  float* att = (float*)&arena[wv][0];

  const float4* d4 = (const float4*)(dist + base);
  const float4* n4 = (const float4*)(ninf + base);

  // ---- P0: zero hist ----
#pragma unroll
  for (int k = 0; k < 16; ++k) hist[lane + 64 * k] = 0u;
  WSYNC();

  // ---- P1: stream row (deep-clustered loads) + value histogram ----
  {
    float4 dreg[20], nreg[20];
#pragma unroll
    for (int t = 0; t < 20; ++t) {
      int i4 = lane + 64 * t;
      if (i4 < NI4) { dreg[t] = d4[i4]; nreg[t] = n4[i4]; }
    }
#pragma unroll
    for (int t = 0; t < 20; ++t) {
      int i4 = lane + 64 * t;
      if (i4 < NI4) {
#pragma unroll
        for (int c = 0; c < 4; ++c) {
          float v = (&dreg[t].x)[c] - (&nreg[t].x)[c];
          atomicAdd(&hist[HMAP(vbin(v))], 1u);
        }
      }
    }
  }
  WSYNC();

  // ---- P2: in-wave scan of 1024 bins, find pivot bin ----
  unsigned int bstar, cumB, binc;
  {
    unsigned int s = 0;
#pragma unroll
    for (int k = 0; k < 16; ++k) s += hist[k * 64 + lane];
    unsigned int v = s;
#pragma unroll
    for (int off = 1; off < 64; off <<= 1) {
      unsigned int x = __shfl_up(v, off, 64);
      if (lane >= off) v += x;
    }
    unsigned int cumBefore = v - s;
    bool cross = (cumBefore < (unsigned)L_) && (v >= (unsigned)L_);
    unsigned long long mk = __ballot(cross);
    int src = __ffsll(mk) - 1;
    unsigned int bstarL = 0, cumL = 0, bincL = 0;
    if (cross) {
      unsigned int c = cumBefore; int kk = 0;
      for (; kk < 16; ++kk) {
        unsigned int h = hist[kk * 64 + lane];
        if (c + h >= (unsigned)L_) { bincL = h; break; }
        c += h;
      }
      bstarL = (unsigned)(lane * 16 + kk); cumL = c;
    }
    bstar = (unsigned)__shfl((int)bstarL, src, 64);
    cumB  = (unsigned)__shfl((int)cumL,  src, 64);
    binc  = (unsigned)__shfl((int)bincL, src, 64);
  }
  const bool fb = (cumB + binc > 128u);

  // ---- P3/P4: candidate compaction (common) or exact radix fallback (rare) ----
  if (!fb) {
    sel[lane] = ~0ull; sel[lane + 64] = ~0ull;
    if (lane == 0) cnt8[wv] = 0u;
    WSYNC();
    float4 dreg[20], nreg[20];
#pragma unroll
    for (int t = 0; t < 20; ++t) {
      int i4 = lane + 64 * t;
      if (i4 < NI4) { dreg[t] = d4[i4]; nreg[t] = n4[i4]; }
    }
#pragma unroll
    for (int t = 0; t < 20; ++t) {
      int i4 = lane + 64 * t;
      if (i4 < NI4) {
#pragma unroll
        for (int c = 0; c < 4; ++c) {
          float v = (&dreg[t].x)[c] - (&nreg[t].x)[c];
          if (vbin(v) <= (int)bstar) {
            unsigned long long key = ((unsigned long long)umap(v) << 16) | (unsigned)(i4 * 4 + c);
            unsigned int p = atomicAdd(&cnt8[wv], 1u);
            if (p < 128u) sel[p] = key;
          }
        }
      }
    }
  } else {
    unsigned long long prefix = 0ull;
    unsigned int Krem = L_;
    for (int pass = 0; pass < 6; ++pass) {
      const int shift = 40 - 8 * pass;
#pragma unroll
      for (int k = 0; k < 4; ++k) hist[lane + 64 * k] = 0u;
      WSYNC();
      for (int t = 0; t < 20; ++t) {
        int i4 = lane + 64 * t;
        if (i4 < NI4) {
          float4 dv = d4[i4], nv = n4[i4];
#pragma unroll
          for (int c = 0; c < 4; ++c) {
            float v = (&dv.x)[c] - (&nv.x)[c];
            unsigned long long key = ((unsigned long long)umap(v) << 16) | (unsigned)(i4 * 4 + c);
            if ((key >> (shift + 8)) == prefix)
              atomicAdd(&hist[HMAP4((int)((key >> shift) & 0xFFu))], 1u);
          }
        }
      }
      WSYNC();
      unsigned int s4 = 0;
#pragma unroll
      for (int k = 0; k < 4; ++k) s4 += hist[k * 64 + lane];
      unsigned int v2 = s4;
#pragma unroll
      for (int off = 1; off < 64; off <<= 1) {
        unsigned int x = __shfl_up(v2, off, 64);
        if (lane >= off) v2 += x;
      }
      unsigned int cb = v2 - s4;
      bool cr = (cb < Krem) && (v2 >= Krem);
      unsigned long long mk2 = __ballot(cr);
      int sl = __ffsll(mk2) - 1;
      unsigned int chL = 0, cmL = 0;
      if (cr) {
        unsigned int c = cb; int kk = 0;
        for (; kk < 4; ++kk) {
          unsigned int h = hist[kk * 64 + lane];
          if (c + h >= Krem) break;
          c += h;
        }
        chL = (unsigned)(lane * 4 + kk); cmL = c;
      }
      unsigned int chosen = (unsigned)__shfl((int)chL, sl, 64);
      unsigned int cum2   = (unsigned)__shfl((int)cmL, sl, 64);
      prefix = (prefix << 8) | chosen;
      Krem -= cum2;
      WSYNC();
    }
    const unsigned long long kpiv = prefix;
    sel[lane] = ~0ull; sel[lane + 64] = ~0ull;
    if (lane == 0) cnt8[wv] = 0u;
    WSYNC();
    for (int t = 0; t < 20; ++t) {
      int i4 = lane + 64 * t;
      if (i4 < NI4) {
        float4 dv = d4[i4], nv = n4[i4];
#pragma unroll
        for (int c = 0; c < 4; ++c) {
          float v = (&dv.x)[c] - (&nv.x)[c];
          unsigned long long key = ((unsigned long long)umap(v) << 16) | (unsigned)(i4 * 4 + c);
          if (key <= kpiv) {
            unsigned int p = atomicAdd(&cnt8[wv], 1u);
            if (p < 128u) sel[p] = key;
          }
        }
      }
    }
  }
  WSYNC();

  // ---- P5: rank-by-count sort (distinct keys, <=128) ----
  {
    unsigned long long ka = sel[lane], kb = sel[lane + 64];
    int ra = 0, rb = 0;
#pragma unroll 8
    for (int j2 = 0; j2 < 128; ++j2) {
      unsigned long long kj = sel[j2];
      ra += (kj < ka) ? 1 : 0;
      rb += (kj < kb) ? 1 : 0;
    }
    if (ka != ~0ull) {
      unsigned int u = (unsigned int)(ka >> 16);
      unsigned int bits = (u & 0x80000000u) ? (u ^ 0x80000000u) : ~u;
      sdv[ra] = __uint_as_float(bits);
      idxs[ra] = (unsigned int)(ka & 0xFFFFull);
    }
    if (kb != ~0ull) {
      unsigned int u = (unsigned int)(kb >> 16);
      unsigned int bits = (u & 0x80000000u) ? (u ^ 0x80000000u) : ~u;
      sdv[rb] = __uint_as_float(bits);
      idxs[rb] = (unsigned int)(kb & 0xFFFFull);
    }
  }
  WSYNC();

  // ---- P6: normalize sd in-place; gather theta/mask at sorted idx ----
  const float invn = 1.0f / (sdv[L_ - 1] + 1e-6f);
  {
    const int l1 = lane + 64;
    const int l1g = (l1 < L_) ? l1 : 0;
    unsigned int i0 = idxs[lane], i1 = idxs[l1g];
    float sd0 = sdv[lane], sd1 = sdv[l1g];
    float th0 = theta[base + i0];
    float nm0 = ninf[base + i0];
    float th1 = 0.f, nm1 = 0.f;
    if (l1 < L_) { th1 = theta[base + i1]; nm1 = ninf[base + i1]; }
    stv[lane] = th0; smv[lane] = nm0; sdv[lane] = sd0 * invn;
    if (l1 < L_) { stv[l1] = th1; smv[l1] = nm1; sdv[l1] = sd1 * invn; }
  }
  WSYNC();

  // ---- P7: score + softmax, 8-lane group per head; a0,a1 ----
  const int hh = lane >> 3, jj = lane & 7;
  float w13[13];
  float a0, a1;
  {
    const float c0 = ws[OFF_C0 + hh], c1 = ws[OFF_C1 + hh], c2 = ws[OFF_C2 + hh];
    float mx = -INFINITY;
#pragma unroll
    for (int k = 0; k < 13; ++k) {
      int l = jj + 8 * k;
      float scv = -INFINITY;
      if (l < L_)
        scv = fmaf(sdv[l], c0, fmaf(stv[l], c1, c2 + ws[OFF_POSQ + hh * L_ + l] + smv[l]));
      w13[k] = scv;
      mx = fmaxf(mx, scv);
    }
#pragma unroll
    for (int off = 1; off <= 4; off <<= 1) mx = fmaxf(mx, __shfl_xor(mx, off, 64));
    float sum = 0.f;
#pragma unroll
    for (int k = 0; k < 13; ++k) { float e = expf(w13[k] - mx); w13[k] = e; sum += e; }
#pragma unroll
    for (int off = 1; off <= 4; off <<= 1) sum += __shfl_xor(sum, off, 64);
    const float inv = 1.0f / sum;
    a0 = 0.f; a1 = 0.f;
#pragma unroll
    for (int k = 0; k < 13; ++k) {
      int l = jj + 8 * k; int lc = (l < L_) ? l : 0;
      float wgt = w13[k] * inv; w13[k] = wgt;
      a0 = fmaf(wgt, sdv[lc], a0);
      a1 = fmaf(wgt, stv[lc], a1);
    }
#pragma unroll
    for (int off = 1; off <= 4; off <<= 1) { a0 += __shfl_xor(a0, off, 64); a1 += __shfl_xor(a1, off, 64); }
  }

  // ---- P8: att[hd] via per-lane partials + 8-lane shfl reduce ----
  {
    float part[16];
#pragma unroll
    for (int t = 0; t < 16; ++t) part[t] = 0.f;
#pragma unroll
    for (int k = 0; k < 13; ++k) {
      int l = jj + 8 * k;
      if (l < L_) {
        const float* pv = ws + OFF_PV + l * (H_ * D_) + hh * 16;
        float wgt = w13[k];
#pragma unroll
        for (int t = 0; t < 16; ++t) part[t] = fmaf(wgt, pv[t], part[t]);
      }
    }
#pragma unroll
    for (int off = 1; off <= 4; off <<= 1) {
#pragma unroll
      for (int t = 0; t < 16; ++t) part[t] += __shfl_xor(part[t], off, 64);
    }
#pragma unroll
    for (int t = 0; t < 16; ++t) {   // all 8 lanes of the group write identical values
      int hd = hh * 16 + t;
      att[hd] = fmaf(a0, ws[OFF_PV0 + hd], fmaf(a1, ws[OFF_PV1 + hd], ws[OFF_PVB + hd])) + part[t];
    }
  }
  WSYNC();

  // ---- P9: m0/m1/mb full-wave reduce over att ----
  float m0, m1, mb;
  {
    float x0 = att[lane], x1 = att[lane + 64];
    m0 = fmaf(x0, ws[OFF_WC0 + lane], x1 * ws[OFF_WC0 + lane + 64]);
    m1 = fmaf(x0, ws[OFF_WC1 + lane], x1 * ws[OFF_WC1 + lane + 64]);
    mb = fmaf(x0, ws[OFF_WCB + lane], x1 * ws[OFF_WCB + lane + 64]);
#pragma unroll
    for (int off = 1; off < 64; off <<= 1) {
      m0 += __shfl_xor(m0, off, 64);
      m1 += __shfl_xor(m1, off, 64);
      mb += __shfl_xor(mb, off, 64);
    }
    m0 += ws[OFF_SB + 0]; m1 += ws[OFF_SB + 1]; mb += ws[OFF_SB + 2];
  }

  // ---- P10: s2 for l=lane and l=lane+64 ----
  const int l1 = lane + 64;
  const int l1c = (l1 < L_) ? l1 : 0;
  float s2a = 0.f, s2b = 0.f;
#pragma unroll 8
  for (int hd = 0; hd < H_ * D_; ++hd) {
    float a = att[hd];
    s2a = fmaf(a, ws[OFF_PCT + hd * L_ + lane], s2a);
    s2b = fmaf(a, ws[OFF_PCT + hd * L_ + l1c], s2b);
  }
  const float SC = 0.08838834764831845f;   // 1/sqrt(E)
  float out_a = (fmaf(sdv[lane], m0, fmaf(stv[lane], m1, mb)) + ws[OFF_PCB + lane] + s2a) * SC;
  float out_b = (fmaf(sdv[l1c], m0, fmaf(stv[l1c], m1, mb)) + ws[OFF_PCB + l1c] + s2b) * SC;
  unsigned int ia = idxs[lane];
  unsigned int ib = idxs[l1c];

  // ---- P11: zero row, drain stores, scatter ----
  {
    float4* o4 = (float4*)(out + base);
    const float4 z = make_float4(0.f, 0.f, 0.f, 0.f);
#pragma unroll
    for (int t = 0; t < 20; ++t) {
      int i4 = lane + 64 * t;
      if (i4 < NI4) o4[i4] = z;
    }
  }
  VSYNC();
  out[base + ia] = out_a;
  if (l1 < L_) out[base + ib] = out_b;
}

extern "C" void kernel_launch(void* const* d_in, const int* in_sizes, int n_in,
                              void* d_out, int out_size, void* d_ws, size_t ws_size,
                              hipStream_t stream) {
  const float* dist = (const float*)d_in[0];
  const float* theta = (const float*)d_in[1];
  const float* ninf = (const float*)d_in[2];
  const float* Wi   = (const float*)d_in[3];
  const float* bi   = (const float*)d_in[4];
  const float* cur  = (const float*)d_in[5];
  const float* Wq   = (const float*)d_in[6];
  const float* Wk   = (const float*)d_in[7];
  const float* Wv   = (const float*)d_in[8];
  const float* Wc   = (const float*)d_in[9];
  const float* bcv  = (const float*)d_in[10];
  float* out = (float*)d_out;
  float* ws  = (float*)d_ws;

  precomp<<<dim3(L_ + 1), dim3(128), 0, stream>>>(Wq, Wk, cur, Wi, bi, Wv, Wc, bcv, ws);
  local_att_kernel<<<dim3((B_ * M_) / RPB), dim3(512), 0, stream>>>(dist, theta, ninf, ws, out);
}

// Round 5
// 72.076 us; speedup vs baseline: 3.2194x; 1.1067x over previous
//
#include <hip/hip_runtime.h>
#include <math.h>

#define B_ 32
#define M_ 64
#define N_ 5000
#define L_ 100
#define H_ 8
#define D_ 16
#define E_ 128
#define NBIN 1024
#define NI4 1250   // N_/4
#define NT 128     // threads per block = 2 waves, ONE ROW PER BLOCK

// ---- workspace float offsets ----
#define OFF_POSQ  0        // [8*100] layout [h][l]
#define OFF_C0    800      // [8]
#define OFF_C1    808      // [8]
#define OFF_C2    816      // [8]
#define OFF_PV0   824      // [128]
#define OFF_PV1   952      // [128]
#define OFF_PVB   1080     // [128]
#define OFF_WC0   1208     // [128]
#define OFF_WC1   1336     // [128]
#define OFF_WCB   1464     // [128]
#define OFF_SB    1592     // [3]
#define OFF_PCB   1596     // [100]
#define OFF_PV    1696     // [100*128]  PV[l][hd]
#define OFF_PCT   14496    // [128*100]  PCt[hd][l]

__device__ __forceinline__ int vbin(float v) {
  if (!(v >= 0.f)) return 0;
  if (v >= 1.0f) return NBIN - 1;
  return (int)(v * (float)NBIN);
}
__device__ __forceinline__ unsigned int umap(float v) {
  unsigned int b = __float_as_uint(v);
  return (b & 0x80000000u) ? ~b : (b | 0x80000000u);
}
__device__ __forceinline__ float unmap(unsigned int u) {
  unsigned int b = (u & 0x80000000u) ? (u ^ 0x80000000u) : ~u;
  return __uint_as_float(b);
}
// bank-conflict-free hist layouts for the scan read pattern
#define HMAP8(b) ((((b) & 7) << 7) | ((b) >> 3))   // 1024 bins, 8/thread
#define HMAP2(b) ((((b) & 1) << 7) | ((b) >> 1))   // 256 bins, 2/thread

// ---- fused precomp: block 0 = q-folded vectors; blocks 1..100 = per-l tables ----
__global__ __launch_bounds__(128) void precomp(
    const float* __restrict__ Wq, const float* __restrict__ Wk,
    const float* __restrict__ cur, const float* __restrict__ Wi,
    const float* __restrict__ bi, const float* __restrict__ Wv,
    const float* __restrict__ Wc, const float* __restrict__ bc,
    float* __restrict__ ws)
{
  const int tid = threadIdx.x;
  const int blk = blockIdx.x;
  __shared__ float pr[E_];
  __shared__ float red[8];
  const int lane = tid & 63, wvv = tid >> 6;

  if (blk == 0) {
    float qsv = 0.f;
    for (int e = 0; e < E_; ++e) qsv = fmaf(Wq[tid * E_ + e], cur[e], qsv);
    float wk0=0,wk1=0,wkb=0,pv0=0,pv1=0,pvb=0,wc0=0,wc1=0,wcb=0;
    for (int e = 0; e < E_; ++e) {
      float wi0 = Wi[2*e], wi1 = Wi[2*e+1], bie = bi[e];
      float wk = Wk[tid*E_+e], wvx = Wv[tid*E_+e], wcc = Wc[e*(H_*D_)+tid];
      wk0=fmaf(wk,wi0,wk0);  wk1=fmaf(wk,wi1,wk1);  wkb=fmaf(wk,bie,wkb);
      pv0=fmaf(wvx,wi0,pv0); pv1=fmaf(wvx,wi1,pv1); pvb=fmaf(wvx,bie,pvb);
      wc0=fmaf(wcc,wi0,wc0); wc1=fmaf(wcc,wi1,wc1); wcb=fmaf(wcc,bie,wcb);
    }
    ws[OFF_PV0+tid]=pv0; ws[OFF_PV1+tid]=pv1; ws[OFF_PVB+tid]=pvb;
    ws[OFF_WC0+tid]=wc0; ws[OFF_WC1+tid]=wc1; ws[OFF_WCB+tid]=wcb;
    float c0 = qsv*wk0, c1 = qsv*wk1, c2 = qsv*wkb;
    for (int off = 1; off < 16; off <<= 1) {
      c0 += __shfl_xor(c0, off, 16); c1 += __shfl_xor(c1, off, 16); c2 += __shfl_xor(c2, off, 16);
    }
    if ((tid & 15) == 0) {
      int h = tid >> 4;
      ws[OFF_C0+h] = c0*0.25f; ws[OFF_C1+h] = c1*0.25f; ws[OFF_C2+h] = c2*0.25f;
    }
    float p0 = Wi[2*tid]*bc[tid], p1 = Wi[2*tid+1]*bc[tid], p2 = bi[tid]*bc[tid];
    for (int off = 32; off > 0; off >>= 1) {
      p0 += __shfl_xor(p0, off, 64); p1 += __shfl_xor(p1, off, 64); p2 += __shfl_xor(p2, off, 64);
    }
    if (lane == 0) { red[wvv*3+0]=p0; red[wvv*3+1]=p1; red[wvv*3+2]=p2; }
    __syncthreads();
    if (tid == 0) {
      ws[OFF_SB+0]=red[0]+red[3]; ws[OFF_SB+1]=red[1]+red[4]; ws[OFF_SB+2]=red[2]+red[5];
    }
  } else {
    const int l = blk - 1;
    const float log_inc = 0.14619588050755848f;   // ln(10000)/63
    {
      int j = tid & 63;
      float scaled = (float)l * expf(-(float)j * log_inc);
      pr[tid] = (tid < 64) ? sinf(scaled) : cosf(scaled);
    }
    __syncthreads();
    float qsv=0.f, pwk=0.f, accv=0.f, accc=0.f;
    for (int e = 0; e < E_; ++e) qsv = fmaf(Wq[tid*E_+e], cur[e], qsv);
    for (int e = 0; e < E_; ++e) {
      float p = pr[e];
      pwk  = fmaf(Wk[tid*E_+e], p, pwk);
      accv = fmaf(Wv[tid*E_+e], p, accv);
      accc = fmaf(Wc[e*(H_*D_)+tid], p, accc);
    }
    ws[OFF_PV  + l*(H_*D_) + tid] = accv;
    ws[OFF_PCT + tid*L_ + l] = accc;
    float pq = qsv * pwk;
    for (int off = 1; off < 16; off <<= 1) pq += __shfl_xor(pq, off, 16);
    if ((tid & 15) == 0) ws[OFF_POSQ + (tid>>4)*L_ + l] = pq * 0.25f;
    float pb = pr[tid] * bc[tid];
    for (int off = 32; off > 0; off >>= 1) pb += __shfl_xor(pb, off, 64);
    if (lane == 0) red[wvv] = pb;
    __syncthreads();
    if (tid == 0) ws[OFF_PCB + l] = red[0] + red[1];
  }
}

// ---- main kernel: one block (2 waves) per row ----
__global__ __launch_bounds__(NT, 4) void local_att_kernel(
    const float* __restrict__ dist, const float* __restrict__ theta,
    const float* __restrict__ ninf, const float* __restrict__ ws,
    float* __restrict__ out)
{
  __shared__ unsigned int hist[NBIN];           // 4 KB
  __shared__ unsigned long long sel[128];       // 1 KB
  __shared__ float sdv[128];
  __shared__ unsigned int idxs[128];
  __shared__ float stv[L_], smv[L_];
  __shared__ float att[H_ * D_];
  __shared__ unsigned int bitmap[160];          // 5000 bits
  __shared__ unsigned int hidx[256];
  __shared__ float hval[256];
  __shared__ unsigned int wsum[2];
  __shared__ unsigned int s_bstar, s_cumB, s_binc, s_cnt, s_chosen, s_cumb2;

  const int tid = threadIdx.x;
  const int lane = tid & 63, wv = tid >> 6;
  const size_t base = (size_t)blockIdx.x * N_;
  const float4* d4 = (const float4*)(dist + base);
  const float4* n4 = (const float4*)(ninf + base);

  // ---- P0: init ----
  for (int j = tid; j < NBIN; j += NT) hist[j] = 0u;
  sel[tid] = ~0ull;
  if (tid == 0) s_cnt = 0u;
  __syncthreads();

  // ---- P1: stream row once; keep u in regs; LDS histogram ----
  unsigned int u[40];
#pragma unroll
  for (int t = 0; t < 10; ++t) {
    int i4 = tid + NT * t;
    if (i4 < NI4) {
      float4 dv = d4[i4], nv = n4[i4];
#pragma unroll
      for (int c = 0; c < 4; ++c) {
        float v = (&dv.x)[c] - (&nv.x)[c];
        u[4 * t + c] = umap(v);
        atomicAdd(&hist[HMAP8(vbin(v))], 1u);
      }
    }
  }
  __syncthreads();

  // ---- P2: cross-wave scan of 1024 bins (8/thread), pick pivot bin ----
  {
    unsigned int s = 0;
#pragma unroll
    for (int k = 0; k < 8; ++k) s += hist[(k << 7) | tid];
    unsigned int v = s;
#pragma unroll
    for (int off = 1; off < 64; off <<= 1) {
      unsigned int x = __shfl_up(v, off, 64);
      if (lane >= off) v += x;
    }
    if (lane == 63) wsum[wv] = v;
    __syncthreads();
    if (wv == 1) v += wsum[0];
    unsigned int cumBefore = v - s;
    if (cumBefore < (unsigned)L_ && v >= (unsigned)L_) {   // exactly one thread
      unsigned int c = cumBefore;
#pragma unroll
      for (int k = 0; k < 8; ++k) {
        unsigned int h = hist[(k << 7) | tid];
        if (c + h >= (unsigned)L_) { s_bstar = tid * 8 + k; s_cumB = c; s_binc = h; break; }
        c += h;
      }
    }
    __syncthreads();
  }
  const int bstar = (int)s_bstar;
  const bool fb = (s_cumB + s_binc > 128u);

  // ---- P3: compaction from REGISTERS (common) or exact radix fallback (rare) ----
  if (!fb) {
#pragma unroll
    for (int t = 0; t < 10; ++t) {
      int i4 = tid + NT * t;
      if (i4 < NI4) {
#pragma unroll
        for (int c = 0; c < 4; ++c) {
          unsigned int uu = u[4 * t + c];
          if (vbin(unmap(uu)) <= bstar) {     // exactly consistent with histogram
            unsigned int p = atomicAdd(&s_cnt, 1u);
            if (p < 128u) sel[p] = ((unsigned long long)uu << 16) | (unsigned)(4 * i4 + c);
          }
        }
      }
    }
  } else {
    unsigned long long prefix = 0ull;
    unsigned int Krem = L_;
    for (int pass = 0; pass < 6; ++pass) {
      const int shift = 40 - 8 * pass;
      for (int j = tid; j < 256; j += NT) hist[j] = 0u;
      __syncthreads();
#pragma unroll
      for (int t = 0; t < 10; ++t) {
        int i4 = tid + NT * t;
        if (i4 < NI4) {
#pragma unroll
          for (int c = 0; c < 4; ++c) {
            unsigned long long key = ((unsigned long long)u[4 * t + c] << 16) | (unsigned)(4 * i4 + c);
            if ((key >> (shift + 8)) == prefix) {
              unsigned int b = (unsigned int)(key >> shift) & 0xFFu;
              atomicAdd(&hist[HMAP2(b)], 1u);
            }
          }
        }
      }
      __syncthreads();
      unsigned int s0 = hist[tid];            // bin 2*tid
      unsigned int s1 = hist[128 + tid];      // bin 2*tid+1
      unsigned int s = s0 + s1;
      unsigned int v = s;
#pragma unroll
      for (int off = 1; off < 64; off <<= 1) {
        unsigned int x = __shfl_up(v, off, 64);
        if (lane >= off) v += x;
      }
      if (lane == 63) wsum[wv] = v;
      __syncthreads();
      if (wv == 1) v += wsum[0];
      unsigned int cb = v - s;
      if (cb < Krem && v >= Krem) {
        if (cb + s0 >= Krem) { s_chosen = 2u * tid;     s_cumb2 = cb; }
        else                 { s_chosen = 2u * tid + 1; s_cumb2 = cb + s0; }
      }
      __syncthreads();
      prefix = (prefix << 8) | s_chosen;
      Krem -= s_cumb2;
      __syncthreads();
    }
    const unsigned long long kpiv = prefix;
#pragma unroll
    for (int t = 0; t < 10; ++t) {
      int i4 = tid + NT * t;
      if (i4 < NI4) {
#pragma unroll
        for (int c = 0; c < 4; ++c) {
          unsigned long long key = ((unsigned long long)u[4 * t + c] << 16) | (unsigned)(4 * i4 + c);
          if (key <= kpiv) {
            unsigned int p = atomicAdd(&s_cnt, 1u);
            if (p < 128u) sel[p] = key;
          }
        }
      }
    }
  }
  __syncthreads();

  // ---- P4: rank-by-count sort (distinct keys, <=128) ----
  {
    unsigned long long ka = sel[tid];
    int ra = 0;
#pragma unroll 8
    for (int j = 0; j < 128; ++j) ra += (sel[j] < ka) ? 1 : 0;
    if (ka != ~0ull) {
      unsigned int uu = (unsigned int)(ka >> 16);
      sdv[ra] = unmap(uu);
      idxs[ra] = (unsigned int)(ka & 0xFFFFull);
    }
  }
  __syncthreads();

  // ---- P5: gather theta/mask at sorted idx ----
  const float invn = 1.0f / (sdv[L_ - 1] + 1e-6f);
  if (tid < L_) {
    unsigned int ix = idxs[tid];
    stv[tid] = theta[base + ix];
    smv[tid] = ninf[base + ix];
  }
  __syncthreads();

  // ---- P6: wave0 = score/softmax/att;  wave1 = init bitmap+hash ----
  if (wv == 0) {
    const int hh = lane >> 3, jj = lane & 7;
    float w13[13];
    float a0, a1;
    {
      const float c0 = ws[OFF_C0 + hh], c1 = ws[OFF_C1 + hh], c2 = ws[OFF_C2 + hh];
      float mx = -INFINITY;
#pragma unroll
      for (int k = 0; k < 13; ++k) {
        int l = jj + 8 * k;
        float scv = -INFINITY;
        if (l < L_)
          scv = fmaf(sdv[l] * invn, c0, fmaf(stv[l], c1, c2 + ws[OFF_POSQ + hh * L_ + l] + smv[l]));
        w13[k] = scv;
        mx = fmaxf(mx, scv);
      }
#pragma unroll
      for (int off = 1; off <= 4; off <<= 1) mx = fmaxf(mx, __shfl_xor(mx, off, 64));
      float sum = 0.f;
#pragma unroll
      for (int k = 0; k < 13; ++k) { float e = expf(w13[k] - mx); w13[k] = e; sum += e; }
#pragma unroll
      for (int off = 1; off <= 4; off <<= 1) sum += __shfl_xor(sum, off, 64);
      const float inv = 1.0f / sum;
      a0 = 0.f; a1 = 0.f;
#pragma unroll
      for (int k = 0; k < 13; ++k) {
        int l = jj + 8 * k; int lc = (l < L_) ? l : 0;
        float wgt = w13[k] * inv; w13[k] = wgt;
        a0 = fmaf(wgt, sdv[lc] * invn, a0);
        a1 = fmaf(wgt, stv[lc], a1);
      }
#pragma unroll
      for (int off = 1; off <= 4; off <<= 1) { a0 += __shfl_xor(a0, off, 64); a1 += __shfl_xor(a1, off, 64); }
    }
    {
      float part[16];
#pragma unroll
      for (int t = 0; t < 16; ++t) part[t] = 0.f;
#pragma unroll
      for (int k = 0; k < 13; ++k) {
        int l = jj + 8 * k;
        if (l < L_) {
          const float* pv = ws + OFF_PV + l * (H_ * D_) + hh * 16;
          float wgt = w13[k];
#pragma unroll
          for (int t = 0; t < 16; ++t) part[t] = fmaf(wgt, pv[t], part[t]);
        }
      }
#pragma unroll
      for (int off = 1; off <= 4; off <<= 1) {
#pragma unroll
        for (int t = 0; t < 16; ++t) part[t] += __shfl_xor(part[t], off, 64);
      }
#pragma unroll
      for (int t = 0; t < 16; ++t) {     // 8 lanes write same value to same addr
        int hd = hh * 16 + t;
        att[hd] = fmaf(a0, ws[OFF_PV0 + hd], fmaf(a1, ws[OFF_PV1 + hd], ws[OFF_PVB + hd])) + part[t];
      }
    }
  } else {
    for (int j = lane; j < 160; j += 64) bitmap[j] = 0u;
    for (int j = lane; j < 256; j += 64) hidx[j] = 0xFFFFFFFFu;
  }
  __syncthreads();

  // ---- P7: m0/m1/mb (redundant per wave, 64-wide reduce over att) ----
  float m0, m1, mb;
  {
    float x0 = att[lane], x1 = att[lane + 64];
    m0 = fmaf(x0, ws[OFF_WC0 + lane], x1 * ws[OFF_WC0 + lane + 64]);
    m1 = fmaf(x0, ws[OFF_WC1 + lane], x1 * ws[OFF_WC1 + lane + 64]);
    mb = fmaf(x0, ws[OFF_WCB + lane], x1 * ws[OFF_WCB + lane + 64]);
#pragma unroll
    for (int off = 1; off < 64; off <<= 1) {
      m0 += __shfl_xor(m0, off, 64);
      m1 += __shfl_xor(m1, off, 64);
      mb += __shfl_xor(mb, off, 64);
    }
    m0 += ws[OFF_SB + 0]; m1 += ws[OFF_SB + 1]; mb += ws[OFF_SB + 2];
  }

  // ---- P8: s2[l], insert into hash + bitmap ----
  if (tid < L_) {
    float acc = ws[OFF_PCB + tid];
#pragma unroll 8
    for (int hd = 0; hd < H_ * D_; ++hd) acc = fmaf(att[hd], ws[OFF_PCT + hd * L_ + tid], acc);
    const float SC = 0.08838834764831845f;   // 1/sqrt(E)
    float s2v = (fmaf(sdv[tid] * invn, m0, fmaf(stv[tid], m1, mb)) + acc) * SC;
    unsigned int idx = idxs[tid];
    unsigned int p = idx & 255u;
    while (atomicCAS(&hidx[p], 0xFFFFFFFFu, idx) != 0xFFFFFFFFu) p = (p + 1) & 255u;
    hval[p] = s2v;
    atomicOr(&bitmap[idx >> 5], 1u << (idx & 31));
  }
  __syncthreads();

  // ---- P9: fused zero+scatter coalesced write (each line written once) ----
  float4* o4 = (float4*)(out + base);
#pragma unroll
  for (int t = 0; t < 10; ++t) {
    int i4 = tid + NT * t;
    if (i4 < NI4) {
      unsigned int wbits = (bitmap[i4 >> 3] >> ((i4 & 7) * 4)) & 0xFu;
      float4 o = make_float4(0.f, 0.f, 0.f, 0.f);
      if (wbits) {
#pragma unroll
        for (int c = 0; c < 4; ++c) {
          if ((wbits >> c) & 1u) {
            unsigned int idx = (unsigned int)(4 * i4 + c);
            unsigned int p = idx & 255u;
            while (hidx[p] != idx) p = (p + 1) & 255u;
            (&o.x)[c] = hval[p];
          }
        }
      }
      o4[i4] = o;
    }
  }
}

extern "C" void kernel_launch(void* const* d_in, const int* in_sizes, int n_in,
                              void* d_out, int out_size, void* d_ws, size_t ws_size,
                              hipStream_t stream) {
  const float* dist = (const float*)d_in[0];
  const float* theta = (const float*)d_in[1];
  const float* ninf = (const float*)d_in[2];
  const float* Wi   = (const float*)d_in[3];
  const float* bi   = (const float*)d_in[4];
  const float* cur  = (const float*)d_in[5];
  const float* Wq   = (const float*)d_in[6];
  const float* Wk   = (const float*)d_in[7];
  const float* Wv   = (const float*)d_in[8];
  const float* Wc   = (const float*)d_in[9];
  const float* bcv  = (const float*)d_in[10];
  float* out = (float*)d_out;
  float* ws  = (float*)d_ws;

  precomp<<<dim3(L_ + 1), dim3(128), 0, stream>>>(Wq, Wk, cur, Wi, bi, Wv, Wc, bcv, ws);
  local_att_kernel<<<dim3(B_ * M_), dim3(NT), 0, stream>>>(dist, theta, ninf, ws, out);
}